// Round 5
// baseline (28040.192 us; speedup 1.0000x reference)
//
#include <hip/hip_runtime.h>

typedef unsigned short ushort;
typedef unsigned int uint32;
typedef unsigned long long ull;
typedef __attribute__((ext_vector_type(8))) short bf16x8;
typedef __attribute__((ext_vector_type(4))) float f32x4;

#define BATCH 16
#define TT 2048
#define HID 256

__device__ __forceinline__ ushort f2bf(float f) {
  union { float f; uint32 u; } v; v.f = f;
  uint32 r = v.u + 0x7FFFu + ((v.u >> 16) & 1u);
  return (ushort)(r >> 16);
}
__device__ __forceinline__ float bf2f(ushort u) {
  union { uint32 u; float f; } v; v.u = ((uint32)u) << 16; return v.f;
}
__device__ __forceinline__ float sigm(float x) { return 1.0f / (1.0f + __expf(-x)); }
__device__ __forceinline__ float tanh_fast(float x) { return 1.0f - 2.0f / (__expf(2.0f * x) + 1.0f); }

// ---------------- prep: casts + weight concat + bias sums ----------------
__global__ void prep_kernel(
    const float* __restrict__ x,
    const float* __restrict__ dWih_f, const float* __restrict__ dWih_b,
    const float* __restrict__ l0Wih_f, const float* __restrict__ l0Wih_b,
    const float* __restrict__ l1Wih_f, const float* __restrict__ l1Wih_b,
    const float* __restrict__ dbih_f, const float* __restrict__ dbhh_f,
    const float* __restrict__ dbih_b, const float* __restrict__ dbhh_b,
    const float* __restrict__ l0bih_f, const float* __restrict__ l0bhh_f,
    const float* __restrict__ l0bih_b, const float* __restrict__ l0bhh_b,
    const float* __restrict__ l1bih_f, const float* __restrict__ l1bhh_f,
    const float* __restrict__ l1bih_b, const float* __restrict__ l1bhh_b,
    ushort* __restrict__ xbf, ushort* __restrict__ wA, ushort* __restrict__ wB,
    ushort* __restrict__ wC, float* __restrict__ biasA, float* __restrict__ biasB,
    float* __restrict__ biasC)
{
  int g = blockIdx.x * blockDim.x + threadIdx.x;
  int str = gridDim.x * blockDim.x;
  for (int i = g; i < (BATCH * TT * 256) / 4; i += str) {
    float4 v = ((const float4*)x)[i];
    ushort4 o; o.x = f2bf(v.x); o.y = f2bf(v.y); o.z = f2bf(v.z); o.w = f2bf(v.w);
    ((ushort4*)xbf)[i] = o;
  }
  for (int i = g; i < 2048 * 256; i += str)
    wA[i] = f2bf(i < 1024 * 256 ? dWih_f[i] : dWih_b[i - 1024 * 256]);
  for (int i = g; i < 2048 * 256; i += str)
    wB[i] = f2bf(i < 1024 * 256 ? l0Wih_f[i] : l0Wih_b[i - 1024 * 256]);
  for (int i = g; i < 2048 * 512; i += str)
    wC[i] = f2bf(i < 1024 * 512 ? l1Wih_f[i] : l1Wih_b[i - 1024 * 512]);
  for (int i = g; i < 2048; i += str) {
    biasA[i] = i < 1024 ? dbih_f[i] + dbhh_f[i] : dbih_b[i - 1024] + dbhh_b[i - 1024];
    biasB[i] = i < 1024 ? l0bih_f[i] + l0bhh_f[i] : l0bih_b[i - 1024] + l0bhh_b[i - 1024];
    biasC[i] = i < 1024 ? l1bih_f[i] + l1bhh_f[i] : l1bih_b[i - 1024] + l1bhh_b[i - 1024];
  }
}

// ---------------- GEMM: xp = A[32768,K] * B[2048,K]^T + bias ----------------
// Output layout (per dir): [b][t][pair u/2][gate 0..3][2 units]  (ushort)
__global__ __launch_bounds__(256) void gemm_xp(
    const ushort* __restrict__ A, const ushort* __restrict__ B, int K,
    const float* __restrict__ bias, ushort* __restrict__ xp)
{
  __shared__ __align__(16) ushort lA[128 * 64];
  __shared__ __align__(16) ushort lB[128 * 64];
  const int tid = threadIdx.x;
  const int lane = tid & 63, wv = tid >> 6;
  const int lo = lane & 15, hi = lane >> 4;
  const int wr = wv >> 1, wc = wv & 1;
  const int bm = blockIdx.y * 128, bn = blockIdx.x * 128;

  f32x4 acc[4][4] = {};

  const int nk = K >> 6;
  for (int kt = 0; kt < nk; ++kt) {
    uint4 ra[4], rb[4];
#pragma unroll
    for (int i = 0; i < 4; ++i) {
      int slot = i * 256 + tid;
      int r = slot >> 3, c8 = slot & 7;
      ra[i] = *(const uint4*)(A + (size_t)(bm + r) * K + kt * 64 + c8 * 8);
      rb[i] = *(const uint4*)(B + (size_t)(bn + r) * K + kt * 64 + c8 * 8);
    }
    __syncthreads();
#pragma unroll
    for (int i = 0; i < 4; ++i) {
      int slot = i * 256 + tid;
      int r = slot >> 3, c8 = slot & 7;
      int boff = r * 128 + ((c8 ^ (r & 7)) << 4);
      *(uint4*)((char*)lA + boff) = ra[i];
      *(uint4*)((char*)lB + boff) = rb[i];
    }
    __syncthreads();
#pragma unroll
    for (int kk = 0; kk < 2; ++kk) {
      bf16x8 fa[4], fb[4];
#pragma unroll
      for (int mt = 0; mt < 4; ++mt) {
        int r = wr * 64 + mt * 16 + lo;
        int c8 = kk * 4 + hi;
        fa[mt] = *(const bf16x8*)((const char*)lA + r * 128 + ((c8 ^ (r & 7)) << 4));
      }
#pragma unroll
      for (int nt = 0; nt < 4; ++nt) {
        int r = wc * 64 + nt * 16 + lo;
        int c8 = kk * 4 + hi;
        fb[nt] = *(const bf16x8*)((const char*)lB + r * 128 + ((c8 ^ (r & 7)) << 4));
      }
#pragma unroll
      for (int mt = 0; mt < 4; ++mt)
#pragma unroll
        for (int nt = 0; nt < 4; ++nt)
          acc[mt][nt] = __builtin_amdgcn_mfma_f32_16x16x32_bf16(fa[mt], fb[nt], acc[mt][nt], 0, 0, 0);
    }
  }
#pragma unroll
  for (int nt = 0; nt < 4; ++nt) {
    int n = bn + wc * 64 + nt * 16 + lo;
    float bv = bias[n];
    int dirn = n >> 10;
    int c = n & 1023;
    int gate = c >> 8;
    int u = c & 255;
    size_t base = (size_t)dirn * ((size_t)BATCH * TT * 1024) + (size_t)(u >> 1) * 8 + gate * 2;
#pragma unroll
    for (int mt = 0; mt < 4; ++mt) {
#pragma unroll
      for (int r = 0; r < 4; ++r) {
        float val = acc[mt][nt][r] + bv;
        uint32 h16 = f2bf(val);
        uint32 p16 = (uint32)__shfl_xor((int)h16, 1);
        if (!(lo & 1)) {
          int m = bm + wr * 64 + mt * 16 + hi * 4 + r;
          *(uint32*)(xp + base + (size_t)m * 1024) = h16 | (p16 << 16);
        }
      }
    }
  }
}

// ---------------- LSTM scan body: tagged-word exchange (seqlock) ----------------
// Per (dir, quarter-w) block: 256 thr = 4 waves. 64 hidden units per block.
// Weights register-resident, static indices. h + coeff exchanged as tagged
// 8B words {tag(hi32) | payload(lo32)} via relaxed agent atomics. Tag IS sync.
// MODE 0: dcg (produces tagged coeff). MODE 1: l0 (polls coeff, bf16 out).
// MODE 2: l1 (plain-loads coeff, fp32 out).
template <int MODE>
__device__ __forceinline__ void scan_body(
    const ushort* __restrict__ xp,
    const float* __restrict__ WhhF, const float* __restrict__ WhhB,
    const float* ldsCW, float cbias,
    ull* __restrict__ coefT,              // [2 dir][TT][16] tagged {c+1 | fp32}
    ull* __restrict__ hst_base,           // [2 dir][2 buf][128][16] tagged
    ushort* __restrict__ outBf, float* __restrict__ outF32,
    const int dir, const int w, const int tid)
{
  const int lane = tid & 63, wv = tid >> 6;
  const int lo = lane & 15, hi = lane >> 4;

  const ushort* xpD = xp + (size_t)dir * ((size_t)BATCH * TT * 1024);
  const float* Whh = dir ? WhhB : WhhF;
  ull* hst = hst_base + dir * (2 * 2048);
  ull* coefD = coefT + (size_t)dir * TT * 16;

  const int unit = w * 64 + wv * 16 + lo;
  const int b0 = hi * 4;
  const int sh = (unit & 1) * 16;

  // register-resident weights (B-frags), all indices compile-time
  bf16x8 wfrag[4][8];
#pragma unroll
  for (int gt = 0; gt < 4; ++gt) {
    const float* wrow = Whh + (size_t)(gt * HID + unit) * HID;
#pragma unroll
    for (int kt = 0; kt < 8; ++kt) {
      const float* p = wrow + kt * 32 + hi * 8;
      bf16x8 f;
#pragma unroll
      for (int j = 0; j < 8; ++j) f[j] = (short)f2bf(p[j]);
      wfrag[gt][kt] = f;
    }
  }

  float hprev[4] = {0, 0, 0, 0}, cprev[4] = {0, 0, 0, 0};
  float co[4] = {0, 0, 0, 0};
  uint4 xq0, xq1, xq2, xq3;

  {
    const int t0 = dir ? (TT - 1) : 0;
    const size_t pofs = (size_t)(unit >> 1) * 8;
    xq0 = *(const uint4*)(xpD + ((size_t)(b0 + 0) * TT + t0) * 1024 + pofs);
    xq1 = *(const uint4*)(xpD + ((size_t)(b0 + 1) * TT + t0) * 1024 + pofs);
    xq2 = *(const uint4*)(xpD + ((size_t)(b0 + 2) * TT + t0) * 1024 + pofs);
    xq3 = *(const uint4*)(xpD + ((size_t)(b0 + 3) * TT + t0) * 1024 + pofs);
  }

  bf16x8 af[8];

  for (int s = 0; s < TT; ++s) {
    float xgi[4], xgf[4], xgg[4], xgo[4];
#define XEXT(Q, R) \
    xgi[R] = bf2f((ushort)(Q.x >> sh)); xgf[R] = bf2f((ushort)(Q.y >> sh)); \
    xgg[R] = bf2f((ushort)(Q.z >> sh)); xgo[R] = bf2f((ushort)(Q.w >> sh));
    XEXT(xq0, 0) XEXT(xq1, 1) XEXT(xq2, 2) XEXT(xq3, 3)
#undef XEXT

    f32x4 acc[4] = {};
    if (s > 0) {
      const ull* bp = hst + (s & 1) * 2048 + hi * 64 + lo;
      const ull* cp = coefD + (size_t)s * 16 + b0;
      const uint32 su = (uint32)s;
      while (true) {
        uint32 bad = 0;
#pragma unroll
        for (int kt = 0; kt < 8; ++kt) {
          ull w0 = __hip_atomic_load(bp + kt * 256 +  0, __ATOMIC_RELAXED, __HIP_MEMORY_SCOPE_AGENT);
          ull w1 = __hip_atomic_load(bp + kt * 256 + 16, __ATOMIC_RELAXED, __HIP_MEMORY_SCOPE_AGENT);
          ull w2 = __hip_atomic_load(bp + kt * 256 + 32, __ATOMIC_RELAXED, __HIP_MEMORY_SCOPE_AGENT);
          ull w3 = __hip_atomic_load(bp + kt * 256 + 48, __ATOMIC_RELAXED, __HIP_MEMORY_SCOPE_AGENT);
          union { bf16x8 v; uint32 d[4]; } t;
          t.d[0] = (uint32)w0; t.d[1] = (uint32)w1; t.d[2] = (uint32)w2; t.d[3] = (uint32)w3;
          af[kt] = t.v;
          bad |= ((uint32)(w0 >> 32)) ^ su; bad |= ((uint32)(w1 >> 32)) ^ su;
          bad |= ((uint32)(w2 >> 32)) ^ su; bad |= ((uint32)(w3 >> 32)) ^ su;
        }
        if (MODE == 1) {  // tagged coeff: index s, expected tag s+1
          ull c0 = __hip_atomic_load(cp + 0, __ATOMIC_RELAXED, __HIP_MEMORY_SCOPE_AGENT);
          ull c1 = __hip_atomic_load(cp + 1, __ATOMIC_RELAXED, __HIP_MEMORY_SCOPE_AGENT);
          ull c2 = __hip_atomic_load(cp + 2, __ATOMIC_RELAXED, __HIP_MEMORY_SCOPE_AGENT);
          ull c3 = __hip_atomic_load(cp + 3, __ATOMIC_RELAXED, __HIP_MEMORY_SCOPE_AGENT);
          bad |= ((uint32)(c0 >> 32)) ^ (su + 1); bad |= ((uint32)(c1 >> 32)) ^ (su + 1);
          bad |= ((uint32)(c2 >> 32)) ^ (su + 1); bad |= ((uint32)(c3 >> 32)) ^ (su + 1);
          co[0] = __uint_as_float((uint32)c0); co[1] = __uint_as_float((uint32)c1);
          co[2] = __uint_as_float((uint32)c2); co[3] = __uint_as_float((uint32)c3);
        }
        if (__all(bad == 0)) break;
      }
#pragma unroll
      for (int gt = 0; gt < 4; ++gt) {
        acc[gt] = __builtin_amdgcn_mfma_f32_16x16x32_bf16(af[0], wfrag[gt][0], acc[gt], 0, 0, 0);
        acc[gt] = __builtin_amdgcn_mfma_f32_16x16x32_bf16(af[1], wfrag[gt][1], acc[gt], 0, 0, 0);
        acc[gt] = __builtin_amdgcn_mfma_f32_16x16x32_bf16(af[2], wfrag[gt][2], acc[gt], 0, 0, 0);
        acc[gt] = __builtin_amdgcn_mfma_f32_16x16x32_bf16(af[3], wfrag[gt][3], acc[gt], 0, 0, 0);
        acc[gt] = __builtin_amdgcn_mfma_f32_16x16x32_bf16(af[4], wfrag[gt][4], acc[gt], 0, 0, 0);
        acc[gt] = __builtin_amdgcn_mfma_f32_16x16x32_bf16(af[5], wfrag[gt][5], acc[gt], 0, 0, 0);
        acc[gt] = __builtin_amdgcn_mfma_f32_16x16x32_bf16(af[6], wfrag[gt][6], acc[gt], 0, 0, 0);
        acc[gt] = __builtin_amdgcn_mfma_f32_16x16x32_bf16(af[7], wfrag[gt][7], acc[gt], 0, 0, 0);
      }
    }

#pragma unroll
    for (int r = 0; r < 4; ++r) {
      float gi = acc[0][r] + xgi[r];
      float gf = acc[1][r] + xgf[r];
      float gg = acc[2][r] + xgg[r];
      float go = acc[3][r] + xgo[r];
      float cn = sigm(gf) * cprev[r] + sigm(gi) * tanh_fast(gg);
      float hn = sigm(go) * tanh_fast(cn) + co[r] * hprev[r];
      cprev[r] = cn; hprev[r] = hn;
    }

    // publish h_s tagged into buf[(s+1)&1]
    {
      ull* so = hst + ((s + 1) & 1) * 2048 + (size_t)(w * 32 + wv * 8 + (lo >> 1)) * 16 + b0;
      const ull tg = ((ull)(uint32)(s + 1)) << 32;
#pragma unroll
      for (int r = 0; r < 4; ++r) {
        uint32 h16 = f2bf(hprev[r]);
        uint32 p16 = (uint32)__shfl_xor((int)h16, 1);
        if (!(lo & 1))
          __hip_atomic_store(so + r, (ull)(h16 | (p16 << 16)) | tg,
                             __ATOMIC_RELAXED, __HIP_MEMORY_SCOPE_AGENT);
      }
      asm volatile("" ::: "memory");
    }

    // dcg: coeff for natural index s-1 (tag s) from af = h_{s-1}
    if (MODE == 0 && s > 0 && w == 0 && wv == 0) {
      float part = 0.f;
#pragma unroll
      for (int kt = 0; kt < 8; ++kt) {
        const float* cwp = &ldsCW[kt * 32 + hi * 8];
        f32x4 c0 = *(const f32x4*)cwp;
        f32x4 c1 = *(const f32x4*)(cwp + 4);
#pragma unroll
        for (int j = 0; j < 4; ++j) {
          part += c0[j] * bf2f((ushort)af[kt][j]);
          part += c1[j] * bf2f((ushort)af[kt][4 + j]);
        }
      }
      part += __shfl_xor(part, 16);
      part += __shfl_xor(part, 32);
      if (hi == 0) {
        uint32 pb = __float_as_uint(0.9f * sigm(part + cbias));
        __hip_atomic_store(coefD + (size_t)(s - 1) * 16 + lo, (((ull)(uint32)s) << 32) | pb,
                           __ATOMIC_RELAXED, __HIP_MEMORY_SCOPE_AGENT);
      }
      asm volatile("" ::: "memory");
    }

    const int t_nat = dir ? (TT - 1 - s) : s;
    if (MODE == 1) {
#pragma unroll
      for (int r = 0; r < 4; ++r)
        outBf[((size_t)(b0 + r) * TT + t_nat) * 512 + dir * 256 + unit] = f2bf(hprev[r]);
    } else if (MODE == 2) {
#pragma unroll
      for (int r = 0; r < 4; ++r)
        outF32[((size_t)(b0 + r) * TT + t_nat) * 512 + dir * 256 + unit] = hprev[r];
    }

    // prefetch next step's xp words (+ coeff payload for MODE 2)
    if (s + 1 < TT) {
      const int tn = dir ? (TT - 2 - s) : (s + 1);
      const size_t pofs = (size_t)(unit >> 1) * 8;
      xq0 = *(const uint4*)(xpD + ((size_t)(b0 + 0) * TT + tn) * 1024 + pofs);
      xq1 = *(const uint4*)(xpD + ((size_t)(b0 + 1) * TT + tn) * 1024 + pofs);
      xq2 = *(const uint4*)(xpD + ((size_t)(b0 + 2) * TT + tn) * 1024 + pofs);
      xq3 = *(const uint4*)(xpD + ((size_t)(b0 + 3) * TT + tn) * 1024 + pofs);
      if (MODE == 2) {
        co[0] = __uint_as_float((uint32)coefD[(size_t)(s + 1) * 16 + b0 + 0]);
        co[1] = __uint_as_float((uint32)coefD[(size_t)(s + 1) * 16 + b0 + 1]);
        co[2] = __uint_as_float((uint32)coefD[(size_t)(s + 1) * 16 + b0 + 2]);
        co[3] = __uint_as_float((uint32)coefD[(size_t)(s + 1) * 16 + b0 + 3]);
      }
    }
  }

  // dcg epilogue: coeff index TT-1 (tag TT) from h_{TT-1}
  if (MODE == 0 && w == 0 && wv == 0) {
    const ull* bp = hst + (TT & 1) * 2048 + hi * 64 + lo;
    const uint32 su = (uint32)TT;
    while (true) {
      uint32 bad = 0;
#pragma unroll
      for (int kt = 0; kt < 8; ++kt) {
        ull w0 = __hip_atomic_load(bp + kt * 256 +  0, __ATOMIC_RELAXED, __HIP_MEMORY_SCOPE_AGENT);
        ull w1 = __hip_atomic_load(bp + kt * 256 + 16, __ATOMIC_RELAXED, __HIP_MEMORY_SCOPE_AGENT);
        ull w2 = __hip_atomic_load(bp + kt * 256 + 32, __ATOMIC_RELAXED, __HIP_MEMORY_SCOPE_AGENT);
        ull w3 = __hip_atomic_load(bp + kt * 256 + 48, __ATOMIC_RELAXED, __HIP_MEMORY_SCOPE_AGENT);
        union { bf16x8 v; uint32 d[4]; } t;
        t.d[0] = (uint32)w0; t.d[1] = (uint32)w1; t.d[2] = (uint32)w2; t.d[3] = (uint32)w3;
        af[kt] = t.v;
        bad |= ((uint32)(w0 >> 32)) ^ su; bad |= ((uint32)(w1 >> 32)) ^ su;
        bad |= ((uint32)(w2 >> 32)) ^ su; bad |= ((uint32)(w3 >> 32)) ^ su;
      }
      if (__all(bad == 0)) break;
    }
    float part = 0.f;
#pragma unroll
    for (int kt = 0; kt < 8; ++kt) {
      const float* cwp = &ldsCW[kt * 32 + hi * 8];
      f32x4 c0 = *(const f32x4*)cwp;
      f32x4 c1 = *(const f32x4*)(cwp + 4);
#pragma unroll
      for (int j = 0; j < 4; ++j) {
        part += c0[j] * bf2f((ushort)af[kt][j]);
        part += c1[j] * bf2f((ushort)af[kt][4 + j]);
      }
    }
    part += __shfl_xor(part, 16);
    part += __shfl_xor(part, 32);
    if (hi == 0) {
      uint32 pb = __float_as_uint(0.9f * sigm(part + cbias));
      __hip_atomic_store(coefD + (size_t)(TT - 1) * 16 + lo, (((ull)(uint32)TT) << 32) | pb,
                         __ATOMIC_RELAXED, __HIP_MEMORY_SCOPE_AGENT);
    }
    asm volatile("" ::: "memory");
  }
}

// single-phase kernel (8 blocks): fallback path + phase C
template <int MODE>
__global__ __launch_bounds__(256, 1) void scan_one(
    const ushort* __restrict__ xp,
    const float* __restrict__ WhhF, const float* __restrict__ WhhB,
    const float* __restrict__ cwF, const float* __restrict__ cwB,
    const float* __restrict__ cbF, const float* __restrict__ cbB,
    ull* __restrict__ coefT, ull* __restrict__ hst,
    ushort* __restrict__ outBf, float* __restrict__ outF32)
{
  __shared__ float ldsCW[256];
  const int tid = threadIdx.x;
  const int dir = blockIdx.x >> 2, w = blockIdx.x & 3;
  float cbias = 0.f;
  if (MODE == 0) { ldsCW[tid] = (dir ? cwB : cwF)[tid]; cbias = dir ? cbB[0] : cbF[0]; }
  __syncthreads();
  scan_body<MODE>(xp, WhhF, WhhB, ldsCW, cbias, coefT, hst, outBf, outF32, dir, w, tid);
}

// fused dcg + layer0 (16 blocks): blocks 0-7 dcg, 8-15 l0 (trails via tagged coeff)
__global__ __launch_bounds__(256, 1) void fused_AB(
    const ushort* __restrict__ xpA, const ushort* __restrict__ xpB,
    const float* __restrict__ dWhhF, const float* __restrict__ dWhhB,
    const float* __restrict__ lWhhF, const float* __restrict__ lWhhB,
    const float* __restrict__ cwF, const float* __restrict__ cwB,
    const float* __restrict__ cbF, const float* __restrict__ cbB,
    ull* __restrict__ coefT, ull* __restrict__ hstA, ull* __restrict__ hstB,
    ushort* __restrict__ xcat)
{
  __shared__ float ldsCW[256];
  const int tid = threadIdx.x;
  const int role = blockIdx.x >> 3;
  const int dir = (blockIdx.x >> 2) & 1, w = blockIdx.x & 3;
  float cbias = 0.f;
  if (role == 0) { ldsCW[tid] = (dir ? cwB : cwF)[tid]; cbias = dir ? cbB[0] : cbF[0]; }
  __syncthreads();
  if (role == 0)
    scan_body<0>(xpA, dWhhF, dWhhB, ldsCW, cbias, coefT, hstA,
                 (ushort*)nullptr, (float*)nullptr, dir, w, tid);
  else
    scan_body<1>(xpB, lWhhF, lWhhB, ldsCW, cbias, coefT, hstB,
                 xcat, (float*)nullptr, dir, w, tid);
}

extern "C" void kernel_launch(void* const* d_in, const int* in_sizes, int n_in,
                              void* d_out, int out_size, void* d_ws, size_t ws_size,
                              hipStream_t stream)
{
  const float* x       = (const float*)d_in[0];
  const float* dWih_f  = (const float*)d_in[1];
  const float* dWhh_f  = (const float*)d_in[2];
  const float* dbih_f  = (const float*)d_in[3];
  const float* dbhh_f  = (const float*)d_in[4];
  const float* dWih_b  = (const float*)d_in[5];
  const float* dWhh_b  = (const float*)d_in[6];
  const float* dbih_b  = (const float*)d_in[7];
  const float* dbhh_b  = (const float*)d_in[8];
  const float* l0Wih_f = (const float*)d_in[9];
  const float* l0Whh_f = (const float*)d_in[10];
  const float* l0bih_f = (const float*)d_in[11];
  const float* l0bhh_f = (const float*)d_in[12];
  const float* l0Wih_b = (const float*)d_in[13];
  const float* l0Whh_b = (const float*)d_in[14];
  const float* l0bih_b = (const float*)d_in[15];
  const float* l0bhh_b = (const float*)d_in[16];
  const float* l1Wih_f = (const float*)d_in[17];
  const float* l1Whh_f = (const float*)d_in[18];
  const float* l1bih_f = (const float*)d_in[19];
  const float* l1bhh_f = (const float*)d_in[20];
  const float* l1Wih_b = (const float*)d_in[21];
  const float* l1Whh_b = (const float*)d_in[22];
  const float* l1bih_b = (const float*)d_in[23];
  const float* l1bhh_b = (const float*)d_in[24];
  const float* cw_f    = (const float*)d_in[25];
  const float* cbi_f   = (const float*)d_in[26];
  const float* cw_b    = (const float*)d_in[27];
  const float* cbi_b   = (const float*)d_in[28];

  char* ws = (char*)d_ws;
  constexpr size_t SZ_XP    = 2ull * BATCH * TT * 1024 * 2;   // 128 MB
  constexpr size_t OFF_XPA  = 0;
  constexpr size_t OFF_XCAT = OFF_XPA + SZ_XP;
  constexpr size_t SZ_XCAT  = (size_t)BATCH * TT * 512 * 2;   // 32 MB
  constexpr size_t OFF_XBF  = OFF_XCAT + SZ_XCAT;
  constexpr size_t SZ_XBF   = (size_t)BATCH * TT * 256 * 2;   // 16 MB
  constexpr size_t OFF_WA   = OFF_XBF + SZ_XBF;
  constexpr size_t SZ_WAB   = 2048ull * 256 * 2;
  constexpr size_t OFF_WB   = OFF_WA + SZ_WAB;
  constexpr size_t OFF_WC   = OFF_WB + SZ_WAB;
  constexpr size_t SZ_WC    = 2048ull * 512 * 2;
  constexpr size_t OFF_BA   = OFF_WC + SZ_WC;
  constexpr size_t OFF_BB   = OFF_BA + 8192;
  constexpr size_t OFF_BC   = OFF_BB + 8192;
  constexpr size_t OFF_CO   = OFF_BC + 8192;
  constexpr size_t SZ_CO    = 2ull * TT * 16 * 8;             // tagged coeff, 512 KB
  constexpr size_t OFF_HST  = OFF_CO + SZ_CO;
  constexpr size_t SZ_HST   = 3ull * 2 * 2 * 2048 * 8;        // 3 scans x 64KB tagged
  constexpr size_t OFF_XPB  = OFF_HST + SZ_HST;
  constexpr size_t NEED_SEQ  = OFF_XPB;
  constexpr size_t NEED_FULL = OFF_XPB + SZ_XP;
  if (ws_size < NEED_SEQ) return;
  const bool fuse = (ws_size >= NEED_FULL);

  ushort* xpA   = (ushort*)(ws + OFF_XPA);
  ushort* xpB   = fuse ? (ushort*)(ws + OFF_XPB) : xpA;
  ushort* xcat  = (ushort*)(ws + OFF_XCAT);
  ushort* xbf   = (ushort*)(ws + OFF_XBF);
  ushort* wA    = (ushort*)(ws + OFF_WA);
  ushort* wB    = (ushort*)(ws + OFF_WB);
  ushort* wC    = (ushort*)(ws + OFF_WC);
  float*  biasA = (float*)(ws + OFF_BA);
  float*  biasB = (float*)(ws + OFF_BB);
  float*  biasC = (float*)(ws + OFF_BC);
  ull*    coefT = (ull*)(ws + OFF_CO);
  ull*    hst   = (ull*)(ws + OFF_HST);

  prep_kernel<<<512, 256, 0, stream>>>(
      x, dWih_f, dWih_b, l0Wih_f, l0Wih_b, l1Wih_f, l1Wih_b,
      dbih_f, dbhh_f, dbih_b, dbhh_b, l0bih_f, l0bhh_f, l0bih_b, l0bhh_b,
      l1bih_f, l1bhh_f, l1bih_b, l1bhh_b,
      xbf, wA, wB, wC, biasA, biasB, biasC);
  // clear stale tags every graph replay (h staging + tagged coeff)
  hipMemsetAsync(ws + OFF_CO, 0, SZ_CO + SZ_HST, stream);

  const size_t HSTR = 2 * 2 * 2048;  // ull words per scan staging

  if (fuse) {
    gemm_xp<<<dim3(16, 256), 256, 0, stream>>>(xbf, wA, 256, biasA, xpA);
    gemm_xp<<<dim3(16, 256), 256, 0, stream>>>(xbf, wB, 256, biasB, xpB);
    fused_AB<<<16, 256, 0, stream>>>(xpA, xpB, dWhh_f, dWhh_b, l0Whh_f, l0Whh_b,
                                     cw_f, cw_b, cbi_f, cbi_b,
                                     coefT, hst + 0 * HSTR, hst + 1 * HSTR, xcat);
  } else {
    gemm_xp<<<dim3(16, 256), 256, 0, stream>>>(xbf, wA, 256, biasA, xpA);
    scan_one<0><<<8, 256, 0, stream>>>(xpA, dWhh_f, dWhh_b, cw_f, cw_b, cbi_f, cbi_b,
                                       coefT, hst + 0 * HSTR, (ushort*)nullptr, (float*)nullptr);
    gemm_xp<<<dim3(16, 256), 256, 0, stream>>>(xbf, wB, 256, biasB, xpA);
    scan_one<1><<<8, 256, 0, stream>>>(xpA, l0Whh_f, l0Whh_b, cw_f, cw_b, cbi_f, cbi_b,
                                       coefT, hst + 1 * HSTR, xcat, (float*)nullptr);
  }
  // phase C (xpA reusable in both modes: dcg/l0 done with it)
  gemm_xp<<<dim3(16, 256), 256, 0, stream>>>(xcat, wC, 512, biasC, xpA);
  scan_one<2><<<8, 256, 0, stream>>>(xpA, l1Whh_f, l1Whh_b, cw_f, cw_b, cbi_f, cbi_b,
                                     coefT, hst + 2 * HSTR, (ushort*)nullptr, (float*)d_out);
}

// Round 6
// 18477.795 us; speedup vs baseline: 1.5175x; 1.5175x over previous
//
#include <hip/hip_runtime.h>

typedef unsigned short ushort;
typedef unsigned int uint32;
typedef unsigned long long ull;
typedef __attribute__((ext_vector_type(8))) short bf16x8;
typedef __attribute__((ext_vector_type(4))) float f32x4;

#define BATCH 16
#define TT 2048
#define HID 256

__device__ __forceinline__ ushort f2bf(float f) {
  union { float f; uint32 u; } v; v.f = f;
  uint32 r = v.u + 0x7FFFu + ((v.u >> 16) & 1u);
  return (ushort)(r >> 16);
}
__device__ __forceinline__ float bf2f(ushort u) {
  union { uint32 u; float f; } v; v.u = ((uint32)u) << 16; return v.f;
}
__device__ __forceinline__ float sigm(float x) { return 1.0f / (1.0f + __expf(-x)); }
__device__ __forceinline__ float tanh_fast(float x) { return 1.0f - 2.0f / (__expf(2.0f * x) + 1.0f); }

// ---------------- prep: x cast + l1 weight cast + bias sums ----------------
__global__ void prep_kernel(
    const float* __restrict__ x,
    const float* __restrict__ l1Wih_f, const float* __restrict__ l1Wih_b,
    const float* __restrict__ dbih_f, const float* __restrict__ dbhh_f,
    const float* __restrict__ dbih_b, const float* __restrict__ dbhh_b,
    const float* __restrict__ l0bih_f, const float* __restrict__ l0bhh_f,
    const float* __restrict__ l0bih_b, const float* __restrict__ l0bhh_b,
    const float* __restrict__ l1bih_f, const float* __restrict__ l1bhh_f,
    const float* __restrict__ l1bih_b, const float* __restrict__ l1bhh_b,
    ushort* __restrict__ xbf, ushort* __restrict__ wC,
    float* __restrict__ biasA, float* __restrict__ biasB, float* __restrict__ biasC)
{
  int g = blockIdx.x * blockDim.x + threadIdx.x;
  int str = gridDim.x * blockDim.x;
  for (int i = g; i < (BATCH * TT * 256) / 4; i += str) {
    float4 v = ((const float4*)x)[i];
    ushort4 o; o.x = f2bf(v.x); o.y = f2bf(v.y); o.z = f2bf(v.z); o.w = f2bf(v.w);
    ((ushort4*)xbf)[i] = o;
  }
  for (int i = g; i < 2048 * 512; i += str)
    wC[i] = f2bf(i < 1024 * 512 ? l1Wih_f[i] : l1Wih_b[i - 1024 * 512]);
  for (int i = g; i < 2048; i += str) {
    biasA[i] = i < 1024 ? dbih_f[i] + dbhh_f[i] : dbih_b[i - 1024] + dbhh_b[i - 1024];
    biasB[i] = i < 1024 ? l0bih_f[i] + l0bhh_f[i] : l0bih_b[i - 1024] + l0bhh_b[i - 1024];
    biasC[i] = i < 1024 ? l1bih_f[i] + l1bhh_f[i] : l1bih_b[i - 1024] + l1bhh_b[i - 1024];
  }
}

// ---------------- GEMM (l1 only): xp = A[32768,512] * B[2048,512]^T + bias ----------------
// Output layout (per dir): [b][t][pair u/2][gate 0..3][2 units]  (ushort)
__global__ __launch_bounds__(256) void gemm_xp(
    const ushort* __restrict__ A, const ushort* __restrict__ B, int K,
    const float* __restrict__ bias, ushort* __restrict__ xp)
{
  __shared__ __align__(16) ushort lA[128 * 64];
  __shared__ __align__(16) ushort lB[128 * 64];
  const int tid = threadIdx.x;
  const int lane = tid & 63, wv = tid >> 6;
  const int lo = lane & 15, hi = lane >> 4;
  const int wr = wv >> 1, wc = wv & 1;
  const int bm = blockIdx.y * 128, bn = blockIdx.x * 128;

  f32x4 acc[4][4] = {};

  const int nk = K >> 6;
  for (int kt = 0; kt < nk; ++kt) {
    uint4 ra[4], rb[4];
#pragma unroll
    for (int i = 0; i < 4; ++i) {
      int slot = i * 256 + tid;
      int r = slot >> 3, c8 = slot & 7;
      ra[i] = *(const uint4*)(A + (size_t)(bm + r) * K + kt * 64 + c8 * 8);
      rb[i] = *(const uint4*)(B + (size_t)(bn + r) * K + kt * 64 + c8 * 8);
    }
    __syncthreads();
#pragma unroll
    for (int i = 0; i < 4; ++i) {
      int slot = i * 256 + tid;
      int r = slot >> 3, c8 = slot & 7;
      int boff = r * 128 + ((c8 ^ (r & 7)) << 4);
      *(uint4*)((char*)lA + boff) = ra[i];
      *(uint4*)((char*)lB + boff) = rb[i];
    }
    __syncthreads();
#pragma unroll
    for (int kk = 0; kk < 2; ++kk) {
      bf16x8 fa[4], fb[4];
#pragma unroll
      for (int mt = 0; mt < 4; ++mt) {
        int r = wr * 64 + mt * 16 + lo;
        int c8 = kk * 4 + hi;
        fa[mt] = *(const bf16x8*)((const char*)lA + r * 128 + ((c8 ^ (r & 7)) << 4));
      }
#pragma unroll
      for (int nt = 0; nt < 4; ++nt) {
        int r = wc * 64 + nt * 16 + lo;
        int c8 = kk * 4 + hi;
        fb[nt] = *(const bf16x8*)((const char*)lB + r * 128 + ((c8 ^ (r & 7)) << 4));
      }
#pragma unroll
      for (int mt = 0; mt < 4; ++mt)
#pragma unroll
        for (int nt = 0; nt < 4; ++nt)
          acc[mt][nt] = __builtin_amdgcn_mfma_f32_16x16x32_bf16(fa[mt], fb[nt], acc[mt][nt], 0, 0, 0);
    }
  }
#pragma unroll
  for (int nt = 0; nt < 4; ++nt) {
    int n = bn + wc * 64 + nt * 16 + lo;
    float bv = bias[n];
    int dirn = n >> 10;
    int c = n & 1023;
    int gate = c >> 8;
    int u = c & 255;
    size_t base = (size_t)dirn * ((size_t)BATCH * TT * 1024) + (size_t)(u >> 1) * 8 + gate * 2;
#pragma unroll
    for (int mt = 0; mt < 4; ++mt) {
#pragma unroll
      for (int r = 0; r < 4; ++r) {
        float val = acc[mt][nt][r] + bv;
        uint32 h16 = f2bf(val);
        uint32 p16 = (uint32)__shfl_xor((int)h16, 1);
        if (!(lo & 1)) {
          int m = bm + wr * 64 + mt * 16 + hi * 4 + r;
          *(uint32*)(xp + base + (size_t)m * 1024) = h16 | (p16 << 16);
        }
      }
    }
  }
}

// ---------------- on-the-fly scan (dcg / l0): xg via in-kernel MFMA ----------------
// Per (dir, quarter-w) block: 256 thr = 4 waves, 1 wave/SIMD. 64 units/block.
// Wih AND Whh register-resident B-frags (static indices). Per step:
//   acc = bias_splat; acc += x_t@Wih^T (pre-poll); poll h tags; acc += h@Whh^T.
// h + coeff exchanged as tagged 8B words {tag | payload}, relaxed agent atomics.
// MODE 0: dcg (produces tagged coeff). MODE 1: l0 (polls coeff, writes xcat bf16).
template <int MODE>
__device__ __forceinline__ void scan_fly(
    const ushort* __restrict__ xbf,            // [16][TT][256] bf16
    const float* __restrict__ WihF, const float* __restrict__ WihB,
    const float* __restrict__ WhhF, const float* __restrict__ WhhB,
    const float* __restrict__ biasAll,         // [2048] dir-concat (bih+bhh)
    const float* ldsCW, float cbias,
    ull* __restrict__ coefT,                   // [2 dir][TT][16] tagged {idx+1 | fp32}
    ull* __restrict__ hst_base,                // [2 dir][2 buf][128][16] tagged
    ushort* __restrict__ outBf,
    const int dir, const int w, const int tid)
{
  const int lane = tid & 63, wv = tid >> 6;
  const int lo = lane & 15, hi = lane >> 4;

  const float* Wih = dir ? WihB : WihF;
  const float* Whh = dir ? WhhB : WhhF;
  ull* hst = hst_base + dir * (2 * 2048);
  ull* coefD = coefT + (size_t)dir * TT * 16;

  const int unit = w * 64 + wv * 16 + lo;
  const int b0 = hi * 4;

  // register-resident weights: B-frags, all indices compile-time
  bf16x8 wih[4][8], whh[4][8];
#pragma unroll
  for (int gt = 0; gt < 4; ++gt) {
    const float* r1 = Wih + (size_t)(gt * HID + unit) * HID;
    const float* r2 = Whh + (size_t)(gt * HID + unit) * HID;
#pragma unroll
    for (int kt = 0; kt < 8; ++kt) {
      bf16x8 f1, f2;
#pragma unroll
      for (int j = 0; j < 8; ++j) {
        f1[j] = (short)f2bf(r1[kt * 32 + hi * 8 + j]);
        f2[j] = (short)f2bf(r2[kt * 32 + hi * 8 + j]);
      }
      wih[gt][kt] = f1; whh[gt][kt] = f2;
    }
  }
  float biasv[4];
#pragma unroll
  for (int gt = 0; gt < 4; ++gt) biasv[gt] = biasAll[dir * 1024 + gt * 256 + unit];

  float hprev[4] = {0, 0, 0, 0}, cprev[4] = {0, 0, 0, 0};
  float co[4] = {0, 0, 0, 0};

  // x A-frag raw words for current step (prefetched 1 step ahead):
  // lane row = batch lo, k = kt*32 + hi*8 (+j)
  uint4 xn[8];
  {
    const int t0 = dir ? (TT - 1) : 0;
    const ushort* p = xbf + ((size_t)lo * TT + t0) * 256 + hi * 8;
#pragma unroll
    for (int kt = 0; kt < 8; ++kt) xn[kt] = *(const uint4*)(p + kt * 32);
  }

  bf16x8 af[8];

  for (int s = 0; s < TT; ++s) {
    // ---- 1) acc = bias + x_t @ Wih^T (independent of h; pre-poll) ----
    bf16x8 xa[8];
#pragma unroll
    for (int kt = 0; kt < 8; ++kt) {
      union { uint4 u; bf16x8 v; } t; t.u = xn[kt]; xa[kt] = t.v;
    }
    f32x4 acc[4];
#pragma unroll
    for (int gt = 0; gt < 4; ++gt) {
      acc[gt] = (f32x4){biasv[gt], biasv[gt], biasv[gt], biasv[gt]};
      acc[gt] = __builtin_amdgcn_mfma_f32_16x16x32_bf16(xa[0], wih[gt][0], acc[gt], 0, 0, 0);
      acc[gt] = __builtin_amdgcn_mfma_f32_16x16x32_bf16(xa[1], wih[gt][1], acc[gt], 0, 0, 0);
      acc[gt] = __builtin_amdgcn_mfma_f32_16x16x32_bf16(xa[2], wih[gt][2], acc[gt], 0, 0, 0);
      acc[gt] = __builtin_amdgcn_mfma_f32_16x16x32_bf16(xa[3], wih[gt][3], acc[gt], 0, 0, 0);
      acc[gt] = __builtin_amdgcn_mfma_f32_16x16x32_bf16(xa[4], wih[gt][4], acc[gt], 0, 0, 0);
      acc[gt] = __builtin_amdgcn_mfma_f32_16x16x32_bf16(xa[5], wih[gt][5], acc[gt], 0, 0, 0);
      acc[gt] = __builtin_amdgcn_mfma_f32_16x16x32_bf16(xa[6], wih[gt][6], acc[gt], 0, 0, 0);
      acc[gt] = __builtin_amdgcn_mfma_f32_16x16x32_bf16(xa[7], wih[gt][7], acc[gt], 0, 0, 0);
    }

    // ---- 2) prefetch next step's x words (long latency budget) ----
    if (s + 1 < TT) {
      const int tn = dir ? (TT - 2 - s) : (s + 1);
      const ushort* p = xbf + ((size_t)lo * TT + tn) * 256 + hi * 8;
#pragma unroll
      for (int kt = 0; kt < 8; ++kt) xn[kt] = *(const uint4*)(p + kt * 32);
    }

    // ---- 3) poll tagged h_{s-1} (+ coeff for MODE 1), then h MFMAs ----
    if (s > 0) {
      const ull* bp = hst + (s & 1) * 2048 + hi * 64 + lo;
      const ull* cp = coefD + (size_t)s * 16 + b0;
      const uint32 su = (uint32)s;
      while (true) {
        uint32 bad = 0;
#pragma unroll
        for (int kt = 0; kt < 8; ++kt) {
          ull w0 = __hip_atomic_load(bp + kt * 256 +  0, __ATOMIC_RELAXED, __HIP_MEMORY_SCOPE_AGENT);
          ull w1 = __hip_atomic_load(bp + kt * 256 + 16, __ATOMIC_RELAXED, __HIP_MEMORY_SCOPE_AGENT);
          ull w2 = __hip_atomic_load(bp + kt * 256 + 32, __ATOMIC_RELAXED, __HIP_MEMORY_SCOPE_AGENT);
          ull w3 = __hip_atomic_load(bp + kt * 256 + 48, __ATOMIC_RELAXED, __HIP_MEMORY_SCOPE_AGENT);
          union { bf16x8 v; uint32 d[4]; } t;
          t.d[0] = (uint32)w0; t.d[1] = (uint32)w1; t.d[2] = (uint32)w2; t.d[3] = (uint32)w3;
          af[kt] = t.v;
          bad |= ((uint32)(w0 >> 32)) ^ su; bad |= ((uint32)(w1 >> 32)) ^ su;
          bad |= ((uint32)(w2 >> 32)) ^ su; bad |= ((uint32)(w3 >> 32)) ^ su;
        }
        if (MODE == 1) {  // tagged coeff: natural index s, expected tag s+1
          ull c0 = __hip_atomic_load(cp + 0, __ATOMIC_RELAXED, __HIP_MEMORY_SCOPE_AGENT);
          ull c1 = __hip_atomic_load(cp + 1, __ATOMIC_RELAXED, __HIP_MEMORY_SCOPE_AGENT);
          ull c2 = __hip_atomic_load(cp + 2, __ATOMIC_RELAXED, __HIP_MEMORY_SCOPE_AGENT);
          ull c3 = __hip_atomic_load(cp + 3, __ATOMIC_RELAXED, __HIP_MEMORY_SCOPE_AGENT);
          bad |= ((uint32)(c0 >> 32)) ^ (su + 1); bad |= ((uint32)(c1 >> 32)) ^ (su + 1);
          bad |= ((uint32)(c2 >> 32)) ^ (su + 1); bad |= ((uint32)(c3 >> 32)) ^ (su + 1);
          co[0] = __uint_as_float((uint32)c0); co[1] = __uint_as_float((uint32)c1);
          co[2] = __uint_as_float((uint32)c2); co[3] = __uint_as_float((uint32)c3);
        }
        if (__all(bad == 0)) break;
      }
#pragma unroll
      for (int gt = 0; gt < 4; ++gt) {
        acc[gt] = __builtin_amdgcn_mfma_f32_16x16x32_bf16(af[0], whh[gt][0], acc[gt], 0, 0, 0);
        acc[gt] = __builtin_amdgcn_mfma_f32_16x16x32_bf16(af[1], whh[gt][1], acc[gt], 0, 0, 0);
        acc[gt] = __builtin_amdgcn_mfma_f32_16x16x32_bf16(af[2], whh[gt][2], acc[gt], 0, 0, 0);
        acc[gt] = __builtin_amdgcn_mfma_f32_16x16x32_bf16(af[3], whh[gt][3], acc[gt], 0, 0, 0);
        acc[gt] = __builtin_amdgcn_mfma_f32_16x16x32_bf16(af[4], whh[gt][4], acc[gt], 0, 0, 0);
        acc[gt] = __builtin_amdgcn_mfma_f32_16x16x32_bf16(af[5], whh[gt][5], acc[gt], 0, 0, 0);
        acc[gt] = __builtin_amdgcn_mfma_f32_16x16x32_bf16(af[6], whh[gt][6], acc[gt], 0, 0, 0);
        acc[gt] = __builtin_amdgcn_mfma_f32_16x16x32_bf16(af[7], whh[gt][7], acc[gt], 0, 0, 0);
      }
    }

    // ---- 4) gates (bias + xg already inside acc) ----
#pragma unroll
    for (int r = 0; r < 4; ++r) {
      float gi = acc[0][r];
      float gf = acc[1][r];
      float gg = acc[2][r];
      float go = acc[3][r];
      float cn = sigm(gf) * cprev[r] + sigm(gi) * tanh_fast(gg);
      float hn = sigm(go) * tanh_fast(cn) + co[r] * hprev[r];
      cprev[r] = cn; hprev[r] = hn;
    }

    // ---- 5) publish h_s tagged into buf[(s+1)&1] ----
    {
      ull* so = hst + ((s + 1) & 1) * 2048 + (size_t)(w * 32 + wv * 8 + (lo >> 1)) * 16 + b0;
      const ull tg = ((ull)(uint32)(s + 1)) << 32;
#pragma unroll
      for (int r = 0; r < 4; ++r) {
        uint32 h16 = f2bf(hprev[r]);
        uint32 p16 = (uint32)__shfl_xor((int)h16, 1);
        if (!(lo & 1))
          __hip_atomic_store(so + r, (ull)(h16 | (p16 << 16)) | tg,
                             __ATOMIC_RELAXED, __HIP_MEMORY_SCOPE_AGENT);
      }
      asm volatile("" ::: "memory");
    }

    // ---- 6) dcg: coeff natural index s-1 (tag s) from af = h_{s-1} ----
    if (MODE == 0 && s > 0 && w == 0 && wv == 0) {
      float part = 0.f;
#pragma unroll
      for (int kt = 0; kt < 8; ++kt) {
        const float* cwp = &ldsCW[kt * 32 + hi * 8];
        f32x4 c0 = *(const f32x4*)cwp;
        f32x4 c1 = *(const f32x4*)(cwp + 4);
#pragma unroll
        for (int j = 0; j < 4; ++j) {
          part += c0[j] * bf2f((ushort)af[kt][j]);
          part += c1[j] * bf2f((ushort)af[kt][4 + j]);
        }
      }
      part += __shfl_xor(part, 16);
      part += __shfl_xor(part, 32);
      if (hi == 0) {
        uint32 pb = __float_as_uint(0.9f * sigm(part + cbias));
        __hip_atomic_store(coefD + (size_t)(s - 1) * 16 + lo, (((ull)(uint32)s) << 32) | pb,
                           __ATOMIC_RELAXED, __HIP_MEMORY_SCOPE_AGENT);
      }
      asm volatile("" ::: "memory");
    }

    // ---- 7) l0 output (bf16 concat layout) ----
    if (MODE == 1) {
      const int t_nat = dir ? (TT - 1 - s) : s;
#pragma unroll
      for (int r = 0; r < 4; ++r)
        outBf[((size_t)(b0 + r) * TT + t_nat) * 512 + dir * 256 + unit] = f2bf(hprev[r]);
    }
  }

  // dcg epilogue: coeff index TT-1 (tag TT) from h_{TT-1}
  if (MODE == 0 && w == 0 && wv == 0) {
    const ull* bp = hst + (TT & 1) * 2048 + hi * 64 + lo;
    const uint32 su = (uint32)TT;
    while (true) {
      uint32 bad = 0;
#pragma unroll
      for (int kt = 0; kt < 8; ++kt) {
        ull w0 = __hip_atomic_load(bp + kt * 256 +  0, __ATOMIC_RELAXED, __HIP_MEMORY_SCOPE_AGENT);
        ull w1 = __hip_atomic_load(bp + kt * 256 + 16, __ATOMIC_RELAXED, __HIP_MEMORY_SCOPE_AGENT);
        ull w2 = __hip_atomic_load(bp + kt * 256 + 32, __ATOMIC_RELAXED, __HIP_MEMORY_SCOPE_AGENT);
        ull w3 = __hip_atomic_load(bp + kt * 256 + 48, __ATOMIC_RELAXED, __HIP_MEMORY_SCOPE_AGENT);
        union { bf16x8 v; uint32 d[4]; } t;
        t.d[0] = (uint32)w0; t.d[1] = (uint32)w1; t.d[2] = (uint32)w2; t.d[3] = (uint32)w3;
        af[kt] = t.v;
        bad |= ((uint32)(w0 >> 32)) ^ su; bad |= ((uint32)(w1 >> 32)) ^ su;
        bad |= ((uint32)(w2 >> 32)) ^ su; bad |= ((uint32)(w3 >> 32)) ^ su;
      }
      if (__all(bad == 0)) break;
    }
    float part = 0.f;
#pragma unroll
    for (int kt = 0; kt < 8; ++kt) {
      const float* cwp = &ldsCW[kt * 32 + hi * 8];
      f32x4 c0 = *(const f32x4*)cwp;
      f32x4 c1 = *(const f32x4*)(cwp + 4);
#pragma unroll
      for (int j = 0; j < 4; ++j) {
        part += c0[j] * bf2f((ushort)af[kt][j]);
        part += c1[j] * bf2f((ushort)af[kt][4 + j]);
      }
    }
    part += __shfl_xor(part, 16);
    part += __shfl_xor(part, 32);
    if (hi == 0) {
      uint32 pb = __float_as_uint(0.9f * sigm(part + cbias));
      __hip_atomic_store(coefD + (size_t)(TT - 1) * 16 + lo, (((ull)(uint32)TT) << 32) | pb,
                         __ATOMIC_RELAXED, __HIP_MEMORY_SCOPE_AGENT);
    }
    asm volatile("" ::: "memory");
  }
}

// fused dcg + layer0: 16 blocks (0-7 dcg, 8-15 l0 trailing via tagged coeff)
__global__ __launch_bounds__(256, 1) void fused_AB(
    const ushort* __restrict__ xbf,
    const float* __restrict__ dWihF, const float* __restrict__ dWihB,
    const float* __restrict__ dWhhF, const float* __restrict__ dWhhB,
    const float* __restrict__ lWihF, const float* __restrict__ lWihB,
    const float* __restrict__ lWhhF, const float* __restrict__ lWhhB,
    const float* __restrict__ biasA, const float* __restrict__ biasB,
    const float* __restrict__ cwF, const float* __restrict__ cwB,
    const float* __restrict__ cbF, const float* __restrict__ cbB,
    ull* __restrict__ coefT, ull* __restrict__ hstA, ull* __restrict__ hstB,
    ushort* __restrict__ xcat)
{
  __shared__ float ldsCW[256];
  const int tid = threadIdx.x;
  const int role = blockIdx.x >> 3;
  const int dir = (blockIdx.x >> 2) & 1, w = blockIdx.x & 3;
  float cbias = 0.f;
  if (role == 0) { ldsCW[tid] = (dir ? cwB : cwF)[tid]; cbias = dir ? cbB[0] : cbF[0]; }
  __syncthreads();
  if (role == 0)
    scan_fly<0>(xbf, dWihF, dWihB, dWhhF, dWhhB, biasA, ldsCW, cbias,
                coefT, hstA, (ushort*)nullptr, dir, w, tid);
  else
    scan_fly<1>(xbf, lWihF, lWihB, lWhhF, lWhhB, biasB, ldsCW, 0.f,
                coefT, hstB, xcat, dir, w, tid);
}

// ---------------- l1 scan (MODE 2 of old body): xp precomputed, coeff plain ----------------
__global__ __launch_bounds__(256, 1) void scan_l1(
    const ushort* __restrict__ xp,
    const float* __restrict__ WhhF, const float* __restrict__ WhhB,
    ull* __restrict__ coefT, ull* __restrict__ hst_base,
    float* __restrict__ outF32)
{
  const int tid = threadIdx.x;
  const int lane = tid & 63, wv = tid >> 6;
  const int lo = lane & 15, hi = lane >> 4;
  const int dir = blockIdx.x >> 2, w = blockIdx.x & 3;

  const ushort* xpD = xp + (size_t)dir * ((size_t)BATCH * TT * 1024);
  const float* Whh = dir ? WhhB : WhhF;
  ull* hst = hst_base + dir * (2 * 2048);
  ull* coefD = coefT + (size_t)dir * TT * 16;

  const int unit = w * 64 + wv * 16 + lo;
  const int b0 = hi * 4;
  const int sh = (unit & 1) * 16;

  bf16x8 wfrag[4][8];
#pragma unroll
  for (int gt = 0; gt < 4; ++gt) {
    const float* wrow = Whh + (size_t)(gt * HID + unit) * HID;
#pragma unroll
    for (int kt = 0; kt < 8; ++kt) {
      const float* p = wrow + kt * 32 + hi * 8;
      bf16x8 f;
#pragma unroll
      for (int j = 0; j < 8; ++j) f[j] = (short)f2bf(p[j]);
      wfrag[gt][kt] = f;
    }
  }

  float hprev[4] = {0, 0, 0, 0}, cprev[4] = {0, 0, 0, 0};
  float co[4] = {0, 0, 0, 0};
  uint4 xq0, xq1, xq2, xq3;
  {
    const int t0 = dir ? (TT - 1) : 0;
    const size_t pofs = (size_t)(unit >> 1) * 8;
    xq0 = *(const uint4*)(xpD + ((size_t)(b0 + 0) * TT + t0) * 1024 + pofs);
    xq1 = *(const uint4*)(xpD + ((size_t)(b0 + 1) * TT + t0) * 1024 + pofs);
    xq2 = *(const uint4*)(xpD + ((size_t)(b0 + 2) * TT + t0) * 1024 + pofs);
    xq3 = *(const uint4*)(xpD + ((size_t)(b0 + 3) * TT + t0) * 1024 + pofs);
  }

  bf16x8 af[8];
  for (int s = 0; s < TT; ++s) {
    float xgi[4], xgf[4], xgg[4], xgo[4];
#define XEXT(Q, R) \
    xgi[R] = bf2f((ushort)(Q.x >> sh)); xgf[R] = bf2f((ushort)(Q.y >> sh)); \
    xgg[R] = bf2f((ushort)(Q.z >> sh)); xgo[R] = bf2f((ushort)(Q.w >> sh));
    XEXT(xq0, 0) XEXT(xq1, 1) XEXT(xq2, 2) XEXT(xq3, 3)
#undef XEXT

    f32x4 acc[4] = {};
    if (s > 0) {
      const ull* bp = hst + (s & 1) * 2048 + hi * 64 + lo;
      const uint32 su = (uint32)s;
      while (true) {
        uint32 bad = 0;
#pragma unroll
        for (int kt = 0; kt < 8; ++kt) {
          ull w0 = __hip_atomic_load(bp + kt * 256 +  0, __ATOMIC_RELAXED, __HIP_MEMORY_SCOPE_AGENT);
          ull w1 = __hip_atomic_load(bp + kt * 256 + 16, __ATOMIC_RELAXED, __HIP_MEMORY_SCOPE_AGENT);
          ull w2 = __hip_atomic_load(bp + kt * 256 + 32, __ATOMIC_RELAXED, __HIP_MEMORY_SCOPE_AGENT);
          ull w3 = __hip_atomic_load(bp + kt * 256 + 48, __ATOMIC_RELAXED, __HIP_MEMORY_SCOPE_AGENT);
          union { bf16x8 v; uint32 d[4]; } t;
          t.d[0] = (uint32)w0; t.d[1] = (uint32)w1; t.d[2] = (uint32)w2; t.d[3] = (uint32)w3;
          af[kt] = t.v;
          bad |= ((uint32)(w0 >> 32)) ^ su; bad |= ((uint32)(w1 >> 32)) ^ su;
          bad |= ((uint32)(w2 >> 32)) ^ su; bad |= ((uint32)(w3 >> 32)) ^ su;
        }
        if (__all(bad == 0)) break;
      }
#pragma unroll
      for (int gt = 0; gt < 4; ++gt) {
        acc[gt] = __builtin_amdgcn_mfma_f32_16x16x32_bf16(af[0], wfrag[gt][0], acc[gt], 0, 0, 0);
        acc[gt] = __builtin_amdgcn_mfma_f32_16x16x32_bf16(af[1], wfrag[gt][1], acc[gt], 0, 0, 0);
        acc[gt] = __builtin_amdgcn_mfma_f32_16x16x32_bf16(af[2], wfrag[gt][2], acc[gt], 0, 0, 0);
        acc[gt] = __builtin_amdgcn_mfma_f32_16x16x32_bf16(af[3], wfrag[gt][3], acc[gt], 0, 0, 0);
        acc[gt] = __builtin_amdgcn_mfma_f32_16x16x32_bf16(af[4], wfrag[gt][4], acc[gt], 0, 0, 0);
        acc[gt] = __builtin_amdgcn_mfma_f32_16x16x32_bf16(af[5], wfrag[gt][5], acc[gt], 0, 0, 0);
        acc[gt] = __builtin_amdgcn_mfma_f32_16x16x32_bf16(af[6], wfrag[gt][6], acc[gt], 0, 0, 0);
        acc[gt] = __builtin_amdgcn_mfma_f32_16x16x32_bf16(af[7], wfrag[gt][7], acc[gt], 0, 0, 0);
      }
    }

#pragma unroll
    for (int r = 0; r < 4; ++r) {
      float gi = acc[0][r] + xgi[r];
      float gf = acc[1][r] + xgf[r];
      float gg = acc[2][r] + xgg[r];
      float go = acc[3][r] + xgo[r];
      float cn = sigm(gf) * cprev[r] + sigm(gi) * tanh_fast(gg);
      float hn = sigm(go) * tanh_fast(cn) + co[r] * hprev[r];
      cprev[r] = cn; hprev[r] = hn;
    }

    {
      ull* so = hst + ((s + 1) & 1) * 2048 + (size_t)(w * 32 + wv * 8 + (lo >> 1)) * 16 + b0;
      const ull tg = ((ull)(uint32)(s + 1)) << 32;
#pragma unroll
      for (int r = 0; r < 4; ++r) {
        uint32 h16 = f2bf(hprev[r]);
        uint32 p16 = (uint32)__shfl_xor((int)h16, 1);
        if (!(lo & 1))
          __hip_atomic_store(so + r, (ull)(h16 | (p16 << 16)) | tg,
                             __ATOMIC_RELAXED, __HIP_MEMORY_SCOPE_AGENT);
      }
      asm volatile("" ::: "memory");
    }

    const int t_nat = dir ? (TT - 1 - s) : s;
#pragma unroll
    for (int r = 0; r < 4; ++r)
      outF32[((size_t)(b0 + r) * TT + t_nat) * 512 + dir * 256 + unit] = hprev[r];

    if (s + 1 < TT) {
      const int tn = dir ? (TT - 2 - s) : (s + 1);
      const size_t pofs = (size_t)(unit >> 1) * 8;
      xq0 = *(const uint4*)(xpD + ((size_t)(b0 + 0) * TT + tn) * 1024 + pofs);
      xq1 = *(const uint4*)(xpD + ((size_t)(b0 + 1) * TT + tn) * 1024 + pofs);
      xq2 = *(const uint4*)(xpD + ((size_t)(b0 + 2) * TT + tn) * 1024 + pofs);
      xq3 = *(const uint4*)(xpD + ((size_t)(b0 + 3) * TT + tn) * 1024 + pofs);
      co[0] = __uint_as_float((uint32)coefD[(size_t)(s + 1) * 16 + b0 + 0]);
      co[1] = __uint_as_float((uint32)coefD[(size_t)(s + 1) * 16 + b0 + 1]);
      co[2] = __uint_as_float((uint32)coefD[(size_t)(s + 1) * 16 + b0 + 2]);
      co[3] = __uint_as_float((uint32)coefD[(size_t)(s + 1) * 16 + b0 + 3]);
    }
  }
}

extern "C" void kernel_launch(void* const* d_in, const int* in_sizes, int n_in,
                              void* d_out, int out_size, void* d_ws, size_t ws_size,
                              hipStream_t stream)
{
  const float* x       = (const float*)d_in[0];
  const float* dWih_f  = (const float*)d_in[1];
  const float* dWhh_f  = (const float*)d_in[2];
  const float* dbih_f  = (const float*)d_in[3];
  const float* dbhh_f  = (const float*)d_in[4];
  const float* dWih_b  = (const float*)d_in[5];
  const float* dWhh_b  = (const float*)d_in[6];
  const float* dbih_b  = (const float*)d_in[7];
  const float* dbhh_b  = (const float*)d_in[8];
  const float* l0Wih_f = (const float*)d_in[9];
  const float* l0Whh_f = (const float*)d_in[10];
  const float* l0bih_f = (const float*)d_in[11];
  const float* l0bhh_f = (const float*)d_in[12];
  const float* l0Wih_b = (const float*)d_in[13];
  const float* l0Whh_b = (const float*)d_in[14];
  const float* l0bih_b = (const float*)d_in[15];
  const float* l0bhh_b = (const float*)d_in[16];
  const float* l1Wih_f = (const float*)d_in[17];
  const float* l1Whh_f = (const float*)d_in[18];
  const float* l1bih_f = (const float*)d_in[19];
  const float* l1bhh_f = (const float*)d_in[20];
  const float* l1Wih_b = (const float*)d_in[21];
  const float* l1Whh_b = (const float*)d_in[22];
  const float* l1bih_b = (const float*)d_in[23];
  const float* l1bhh_b = (const float*)d_in[24];
  const float* cw_f    = (const float*)d_in[25];
  const float* cbi_f   = (const float*)d_in[26];
  const float* cw_b    = (const float*)d_in[27];
  const float* cbi_b   = (const float*)d_in[28];

  char* ws = (char*)d_ws;
  constexpr size_t OFF_XP   = 0;
  constexpr size_t SZ_XP    = 2ull * BATCH * TT * 1024 * 2;   // 128 MB (l1 only)
  constexpr size_t OFF_XCAT = OFF_XP + SZ_XP;
  constexpr size_t SZ_XCAT  = (size_t)BATCH * TT * 512 * 2;   // 32 MB
  constexpr size_t OFF_XBF  = OFF_XCAT + SZ_XCAT;
  constexpr size_t SZ_XBF   = (size_t)BATCH * TT * 256 * 2;   // 16 MB
  constexpr size_t OFF_WC   = OFF_XBF + SZ_XBF;
  constexpr size_t SZ_WC    = 2048ull * 512 * 2;              // 2 MB
  constexpr size_t OFF_BA   = OFF_WC + SZ_WC;
  constexpr size_t OFF_BB   = OFF_BA + 8192;
  constexpr size_t OFF_BC   = OFF_BB + 8192;
  constexpr size_t OFF_CO   = OFF_BC + 8192;
  constexpr size_t SZ_CO    = 2ull * TT * 16 * 8;             // tagged coeff, 512 KB
  constexpr size_t OFF_HST  = OFF_CO + SZ_CO;
  constexpr size_t SZ_HST   = 3ull * 2 * 2 * 2048 * 8;        // 3 staging regions
  constexpr size_t NEED     = OFF_HST + SZ_HST;
  if (ws_size < NEED) return;

  ushort* xp    = (ushort*)(ws + OFF_XP);
  ushort* xcat  = (ushort*)(ws + OFF_XCAT);
  ushort* xbf   = (ushort*)(ws + OFF_XBF);
  ushort* wC    = (ushort*)(ws + OFF_WC);
  float*  biasA = (float*)(ws + OFF_BA);
  float*  biasB = (float*)(ws + OFF_BB);
  float*  biasC = (float*)(ws + OFF_BC);
  ull*    coefT = (ull*)(ws + OFF_CO);
  ull*    hst   = (ull*)(ws + OFF_HST);

  prep_kernel<<<512, 256, 0, stream>>>(
      x, l1Wih_f, l1Wih_b,
      dbih_f, dbhh_f, dbih_b, dbhh_b, l0bih_f, l0bhh_f, l0bih_b, l0bhh_b,
      l1bih_f, l1bhh_f, l1bih_b, l1bhh_b,
      xbf, wC, biasA, biasB, biasC);
  // clear stale tags every replay (tagged coeff + h staging)
  hipMemsetAsync(ws + OFF_CO, 0, SZ_CO + SZ_HST, stream);

  const size_t HSTR = 2 * 2 * 2048;  // ull words per scan staging

  // phase A+B fused: dcg + layer0, xg on-the-fly
  fused_AB<<<16, 256, 0, stream>>>(xbf,
                                   dWih_f, dWih_b, dWhh_f, dWhh_b,
                                   l0Wih_f, l0Wih_b, l0Whh_f, l0Whh_b,
                                   biasA, biasB, cw_f, cw_b, cbi_f, cbi_b,
                                   coefT, hst + 0 * HSTR, hst + 1 * HSTR, xcat);
  // phase C: layer 1 (K=512 input projection precomputed)
  gemm_xp<<<dim3(16, 256), 256, 0, stream>>>(xcat, wC, 512, biasC, xp);
  scan_l1<<<8, 256, 0, stream>>>(xp, l1Whh_f, l1Whh_b, coefT, hst + 2 * HSTR, (float*)d_out);
}